// Round 11
// baseline (428.030 us; speedup 1.0000x reference)
//
#include <hip/hip_runtime.h>
#include <math.h>

#define EPS 1e-5f

__device__ __forceinline__ float waveReduceSum(float v) {
#pragma unroll
    for (int off = 32; off > 0; off >>= 1) v += __shfl_xor(v, off, 64);
    return v;
}

// ================= encoder conv (VALID, k=3): wave-per-oc, lane-per-p =================
template <int IC, int OC, int LIN, bool BN_FIRST, bool HAS_STATS, bool STATS_RELU>
__global__ __launch_bounds__(256) void enc_conv2(const float* __restrict__ xin,
                                                 const float* __restrict__ g, const float* __restrict__ bb,
                                                 const float* __restrict__ s, const float* __restrict__ q,
                                                 const float* __restrict__ w, const float* __restrict__ bias,
                                                 float* __restrict__ out,
                                                 float* __restrict__ so, float* __restrict__ qo) {
    constexpr int LOUT = LIN - 2;
    __shared__ float sc[IC], sh[IC];
    __shared__ float xn[IC * LIN];
    int t = threadIdx.x;
    for (int ic = t; ic < IC; ic += 256) {
        float mean = s[ic] / (float)LIN;
        float var = q[ic] / (float)LIN - mean * mean;
        float scale = g[ic] * rsqrtf(var + EPS);
        sc[ic] = scale; sh[ic] = bb[ic] - mean * scale;
    }
    __syncthreads();
    for (int i = t; i < IC * LIN; i += 256) {
        int ic = i / LIN;
        float xv = xin[i];
        float v;
        if (BN_FIRST) { v = xv * sc[ic] + sh[ic]; v = fmaxf(v, 0.f); }
        else          { xv = fmaxf(xv, 0.f); v = xv * sc[ic] + sh[ic]; }
        xn[i] = v;
    }
    __syncthreads();
    int oc = blockIdx.x * 4 + (t >> 6);
    int p0 = t & 63;
    int p = p0 < LOUT ? p0 : 0;
    const float* woc = w + oc * (IC * 3);
    float acc = 0.f;
#pragma unroll 8
    for (int ic = 0; ic < IC; ic++) {
        const float* xi = xn + ic * LIN;
        const float* wi = woc + ic * 3;   // wave-uniform -> broadcast
        acc += xi[p] * wi[0] + xi[p + 1] * wi[1] + xi[p + 2] * wi[2];
    }
    float val = acc + bias[oc];
    if constexpr (HAS_STATS) {
        float r = (p0 < LOUT) ? (STATS_RELU ? fmaxf(val, 0.f) : val) : 0.f;
        float ssum = waveReduceSum(r);
        float qsum = waveReduceSum(r * r);
        if (p0 == 0) { so[oc] = ssum; qo[oc] = qsum; }
    }
    if (p0 < LOUT) out[oc * LOUT + p0] = val;
}

// ================= convT (k=5, pad=4): wave-per-oc, lane-per-p =================
template <int IC, int OC, int LIN, bool BN_FIRST, bool HAS_STATS, bool STATS_RELU>
__global__ __launch_bounds__(256) void dec_convt2(const float* __restrict__ xin,
                                                  const float* __restrict__ g, const float* __restrict__ bb,
                                                  const float* __restrict__ s, const float* __restrict__ q,
                                                  const float* __restrict__ w, const float* __restrict__ bias,
                                                  float* __restrict__ out,
                                                  float* __restrict__ so, float* __restrict__ qo) {
    constexpr int LOUT = LIN + 4;
    __shared__ float sc[IC], sh[IC];
    __shared__ float xn[IC * LIN];
    int t = threadIdx.x;
    for (int ic = t; ic < IC; ic += 256) {
        float mean = s[ic] / (float)LIN;
        float var = q[ic] / (float)LIN - mean * mean;
        float scale = g[ic] * rsqrtf(var + EPS);
        sc[ic] = scale; sh[ic] = bb[ic] - mean * scale;
    }
    __syncthreads();
    for (int i = t; i < IC * LIN; i += 256) {
        int ic = i / LIN;
        float xv = xin[i];
        float v;
        if (BN_FIRST) { v = xv * sc[ic] + sh[ic]; v = fmaxf(v, 0.f); }
        else          { xv = fmaxf(xv, 0.f); v = xv * sc[ic] + sh[ic]; }
        xn[i] = v;
    }
    __syncthreads();
    int oc = blockIdx.x * 4 + (t >> 6);
    int p = t & 63;
    const float* woc = w + oc * 5;
    float acc = 0.f;
#pragma unroll 8
    for (int ic = 0; ic < IC; ic++) {
        const float* wi = woc + ic * (OC * 5);   // wave-uniform -> broadcast
        const float* xi = xn + ic * LIN;
#pragma unroll
        for (int kk = 0; kk < 5; kk++) {
            int m = p - kk;
            float xv = (m >= 0 && m < LIN) ? xi[m] : 0.f;
            acc += xv * wi[kk];
        }
    }
    float val = acc + bias[oc];
    if constexpr (HAS_STATS) {
        float r = (p < LOUT) ? (STATS_RELU ? fmaxf(val, 0.f) : val) : 0.f;
        float ssum = waveReduceSum(r);
        float qsum = waveReduceSum(r * r);
        if (p == 0) { so[oc] = ssum; qo[oc] = qsum; }
    }
    if (p < LOUT) out[oc * LOUT + p] = val;
}

// ================= K2: e1(1->256,k3)+bn2+relu staged in LDS + e2(256->128,k3), wave-per-oc =================
__global__ __launch_bounds__(256) void k2_enc12(const float* __restrict__ x,
                                                const float* __restrict__ w1,
                                                const float* __restrict__ b1,
                                                const float* __restrict__ g2,
                                                const float* __restrict__ bb2,
                                                const float* __restrict__ w2,
                                                const float* __restrict__ b2,
                                                float* __restrict__ h2,
                                                float* __restrict__ s3, float* __restrict__ q3) {
    __shared__ float xs[33];
    __shared__ float e1n[256 * 33];
    int t = threadIdx.x;
    if (t < 33) xs[t] = x[t];
    __syncthreads();
    {
        float w0 = w1[t * 3], wa = w1[t * 3 + 1], wb = w1[t * 3 + 2], bias = b1[t];
        float vals[31];
        float s = 0.f, q = 0.f;
#pragma unroll
        for (int pp = 0; pp < 31; pp++) {
            float v = xs[pp] * w0 + xs[pp + 1] * wa + xs[pp + 2] * wb + bias;
            vals[pp] = v; s += v; q += v * v;
        }
        float mean = s / 31.f;
        float var = q / 31.f - mean * mean;
        float scale = g2[t] * rsqrtf(var + EPS);
        float shift = bb2[t] - mean * scale;
#pragma unroll
        for (int pp = 0; pp < 31; pp++) {
            float v = vals[pp] * scale + shift;
            e1n[t * 33 + pp] = fmaxf(v, 0.f);
        }
    }
    __syncthreads();
    int oc = blockIdx.x * 4 + (t >> 6);
    int p0 = t & 63;
    int p = p0 < 29 ? p0 : 0;
    const float* woc = w2 + oc * 768;
    float acc = 0.f;
#pragma unroll 8
    for (int ic = 0; ic < 256; ic++) {
        const float* xi = e1n + ic * 33;
        const float* wi = woc + ic * 3;
        acc += xi[p] * wi[0] + xi[p + 1] * wi[1] + xi[p + 2] * wi[2];
    }
    float val = acc + b2[oc];
    float r = (p0 < 29) ? val : 0.f;
    float ssum = waveReduceSum(r);
    float qsum = waveReduceSum(r * r);
    if (p0 == 0) { s3[oc] = ssum; q3[oc] = qsum; }
    if (p0 < 29) h2[oc * 29 + p0] = val;
}

// ================= K5: z = efc_w @ h800 + efc_b (32768 x 800) =================
__global__ __launch_bounds__(256) void k5_gemv1(const float* __restrict__ w,
                                                const float* __restrict__ h,
                                                const float* __restrict__ b,
                                                float* __restrict__ z) {
    int wave = threadIdx.x >> 6;
    int lane = threadIdx.x & 63;
    int row = blockIdx.x * 4 + wave;
    const float4* wr = (const float4*)(w + (size_t)row * 800);
    const float4* hv = (const float4*)h;
    float acc = 0.f;
#pragma unroll
    for (int t = 0; t < 3; t++) {
        float4 a = wr[lane + 64 * t];
        float4 c = hv[lane + 64 * t];
        acc += a.x * c.x + a.y * c.y + a.z * c.z + a.w * c.w;
    }
    if (lane < 8) {
        float4 a = wr[192 + lane];
        float4 c = hv[192 + lane];
        acc += a.x * c.x + a.y * c.y + a.z * c.z + a.w * c.w;
    }
    acc = waveReduceSum(acc);
    if (lane == 0) z[row] = acc + b[row];
}

// ================= K67: Af + powers =================
__global__ __launch_bounds__(1024) void k67_afpow(const float* __restrict__ z, float* __restrict__ pw) {
    int t = threadIdx.x;
    const float4* z4 = (const float4*)z;
    float xy = 0.f, xx = 0.f;
    for (int v = t; v < 8191; v += 1024) {
        float4 a = z4[v];
        float nb = z[4 * v + 4];
        xy += a.x * a.y + a.y * a.z + a.z * a.w + a.w * nb;
        xx += a.x * a.x + a.y * a.y + a.z * a.z + a.w * a.w;
    }
    if (t < 3) {
        int i = 32764 + t;
        xy += z[i] * z[i + 1];
        xx += z[i] * z[i];
    }
    xy = waveReduceSum(xy);
    xx = waveReduceSum(xx);
    __shared__ float sx[16], sy[16];
    __shared__ float afs;
    int wv = t >> 6, ln = t & 63;
    if (ln == 0) { sy[wv] = xy; sx[wv] = xx; }
    __syncthreads();
    if (t == 0) {
        float SY = 0.f, SX = 0.f;
        for (int i = 0; i < 16; i++) { SY += sy[i]; SX += sx[i]; }
        afs = SY / (SX + 0.01f);
    }
    __syncthreads();
    float base0 = afs;
    float4* pw4 = (float4*)pw;
    for (int v = t; v < 8192; v += 1024) {
        float4 r;
        float* rp = (float*)&r;
#pragma unroll
        for (int u = 0; u < 4; u++) {
            int e = 4 * v + u;
            float rr = 1.f, base = base0;
            while (e) { if (e & 1) rr *= base; base *= base; e >>= 1; }
            rp[u] = rr;
        }
        pw4[v] = r;
    }
}

// ================= K8a: partial dual-GEMV, 4 blocks per row (3200 blocks) =================
// quarter q of row j: aligned float4 over w (head = j&3 relative to i_lo), partials -> atomicAdd dsum
__global__ __launch_bounds__(256) void k8a_gemv2(const float* __restrict__ w,
                                                 const float* __restrict__ z,
                                                 const float* __restrict__ pw,
                                                 float* __restrict__ dsum) {
    int bid = blockIdx.x;
    int j = bid >> 2, qd = bid & 3;
    int t = threadIdx.x;
    const float* wr = w + (size_t)j * 32767;
    int i_lo = qd * 8192;
    int i_hi = i_lo + 8192; if (i_hi > 32767) i_hi = 32767;
    int head = j & 3;                 // row byte phase 12j mod 16 -> first aligned i ≡ j (mod 4)
    int first = i_lo + head;          // i_lo % 4 == 0 always
    float a0 = 0.f, a1 = 0.f;
    if (t < head) {
        int i = i_lo + t;
        float wv = wr[i]; a0 += z[i] * wv; a1 += pw[i] * wv;
    }
    int nv4 = (i_hi - first) >> 2;
    const float4* w4 = (const float4*)(wr + first);
    for (int v = t; v < nv4; v += 256) {
        float4 a = w4[v];
        int i = first + 4 * v;
        a0 += z[i] * a.x + z[i + 1] * a.y + z[i + 2] * a.z + z[i + 3] * a.w;
        a1 += pw[i] * a.x + pw[i + 1] * a.y + pw[i + 2] * a.z + pw[i + 3] * a.w;
    }
    int tl = (i_hi - first) & 3;
    int ts = first + 4 * nv4;
    if (t < tl) {
        int i = ts + t;
        float wv = wr[i]; a0 += z[i] * wv; a1 += pw[i] * wv;
    }
    a0 = waveReduceSum(a0);
    a1 = waveReduceSum(a1);
    __shared__ float r0[4], r1[4];
    int wv_ = t >> 6, ln = t & 63;
    if (ln == 0) { r0[wv_] = a0; r1[wv_] = a1; }
    __syncthreads();
    if (t == 0) {
        atomicAdd(&dsum[j],       r0[0] + r0[1] + r0[2] + r0[3]);
        atomicAdd(&dsum[800 + j], r1[0] + r1[1] + r1[2] + r1[3]);
    }
}

// ================= K8b: finalize d = dsum(+bias, z0 scale), dbn4 stats =================
__global__ __launch_bounds__(256) void k8b_fix(const float* __restrict__ dsum,
                                               const float* __restrict__ z,
                                               const float* __restrict__ b,
                                               float* __restrict__ d,
                                               float* __restrict__ s, float* __restrict__ q) {
    int j = blockIdx.x * 256 + threadIdx.x;
    if (j >= 800) return;
    float d0 = dsum[j] + b[j];
    float d1 = z[0] * dsum[800 + j] + b[j];
    d[j] = d0;
    d[800 + j] = d1;
    int c0 = j / 50, c1 = 16 + j / 50;
    atomicAdd(&s[c0], d0); atomicAdd(&q[c0], d0 * d0);
    atomicAdd(&s[c1], d1); atomicAdd(&q[c1], d1 * d1);
}

// ================= K12: dbn1+relu + convT d1 (256->1,k3) -> out(64), wave-per-output =================
__global__ __launch_bounds__(256) void k12_dec1(const float* __restrict__ h6,
                                                const float* __restrict__ g, const float* __restrict__ bb,
                                                const float* __restrict__ s, const float* __restrict__ q,
                                                const float* __restrict__ w, const float* __restrict__ b1,
                                                float* __restrict__ out) {
    __shared__ float sc[256], sh[256];
    int t = threadIdx.x;
    {
        float mean = s[t] / 62.f;
        float var = q[t] / 62.f - mean * mean;
        float scale = g[t] * rsqrtf(var + EPS);
        sc[t] = scale; sh[t] = bb[t] - mean * scale;
    }
    __syncthreads();
    int p = blockIdx.x * 4 + (t >> 6);
    int lane = t & 63;
    float acc = 0.f;
#pragma unroll
    for (int i = 0; i < 12; i++) {
        int j = 64 * i + lane;
        int ic = j / 3, kk = j - ic * 3;
        int m = p - kk;
        if (m >= 0 && m < 62) {
            float v = h6[ic * 62 + m] * sc[ic] + sh[ic];
            v = fmaxf(v, 0.f);
            acc += v * w[j];
        }
    }
    acc = waveReduceSum(acc);
    if (lane == 0) out[p] = acc + b1[0];
}

// ================= launcher =================
extern "C" void kernel_launch(void* const* d_in, const int* in_sizes, int n_in,
                              void* d_out, int out_size, void* d_ws, size_t ws_size,
                              hipStream_t stream) {
    const float* x      = (const float*)d_in[0];
    const float* e1_w   = (const float*)d_in[1];
    const float* e1_b   = (const float*)d_in[2];
    const float* bn2_g  = (const float*)d_in[3];
    const float* bn2_b  = (const float*)d_in[4];
    const float* e2_w   = (const float*)d_in[5];
    const float* e2_b   = (const float*)d_in[6];
    const float* bn3_g  = (const float*)d_in[7];
    const float* bn3_b  = (const float*)d_in[8];
    const float* e3_w   = (const float*)d_in[9];
    const float* e3_b   = (const float*)d_in[10];
    const float* bn4_g  = (const float*)d_in[11];
    const float* bn4_b  = (const float*)d_in[12];
    const float* e4_w   = (const float*)d_in[13];
    const float* e4_b   = (const float*)d_in[14];
    const float* efc_w  = (const float*)d_in[15];
    const float* efc_b  = (const float*)d_in[16];
    const float* dfc_w  = (const float*)d_in[17];
    const float* dfc_b  = (const float*)d_in[18];
    const float* dbn4_g = (const float*)d_in[19];
    const float* dbn4_b = (const float*)d_in[20];
    const float* d4_w   = (const float*)d_in[21];
    const float* d4_b   = (const float*)d_in[22];
    const float* dbn3_g = (const float*)d_in[23];
    const float* dbn3_b = (const float*)d_in[24];
    const float* d3_w   = (const float*)d_in[25];
    const float* d3_b   = (const float*)d_in[26];
    const float* dbn2_g = (const float*)d_in[27];
    const float* dbn2_b = (const float*)d_in[28];
    const float* d2_w   = (const float*)d_in[29];
    const float* d2_b   = (const float*)d_in[30];
    const float* dbn1_g = (const float*)d_in[31];
    const float* dbn1_b = (const float*)d_in[32];
    const float* d1_w   = (const float*)d_in[33];
    const float* d1_b   = (const float*)d_in[34];
    float* out = (float*)d_out;

    float* W = (float*)d_ws;
    float* bn3s  = W + 0;    float* bn3q  = W + 128;
    float* bn4s  = W + 256;  float* bn4q  = W + 320;
    float* dbn4s = W + 384;  float* dbn4q = W + 416;
    float* dbn3s = W + 448;  float* dbn3q = W + 512;
    float* dbn2s = W + 576;  float* dbn2q = W + 704;
    float* dbn1s = W + 832;  float* dbn1q = W + 1088;   // stats end at 1344
    float* dsum  = W + 1344;   // 1600 partials (zeroed)
    float* h2    = W + 2944;   // 128*29
    float* h3    = W + 6656;   // 64*27
    float* h800  = W + 8384;   // 800 (16B aligned)
    float* z     = W + 9184;   // 32768 (16B aligned)
    float* pw    = W + 41952;  // 32768 (16B aligned)
    float* dvec  = W + 74720;  // 1600
    float* h4    = W + 76320;  // 64*54
    float* h5    = W + 79776;  // 128*58
    float* h6    = W + 87200;  // 256*62

    // zero BN-stat accumulators + dsum partials
    hipMemsetAsync(d_ws, 0, 2944 * sizeof(float), stream);

    // encoder
    k2_enc12<<<32, 256, 0, stream>>>(x, e1_w, e1_b, bn2_g, bn2_b, e2_w, e2_b, h2, bn3s, bn3q);
    enc_conv2<128, 64, 29, true, true, true><<<16, 256, 0, stream>>>(
        h2, bn3_g, bn3_b, bn3s, bn3q, e3_w, e3_b, h3, bn4s, bn4q);
    enc_conv2<64, 32, 27, false, false, false><<<8, 256, 0, stream>>>(
        h3, bn4_g, bn4_b, bn4s, bn4q, e4_w, e4_b, h800, nullptr, nullptr);
    // FC encoder
    k5_gemv1<<<8192, 256, 0, stream>>>(efc_w, h800, efc_b, z);
    k67_afpow<<<1, 1024, 0, stream>>>(z, pw);
    // FC decoder: split rows 4-way for HBM-stream parallelism, then fixup
    k8a_gemv2<<<3200, 256, 0, stream>>>(dfc_w, z, pw, dsum);
    k8b_fix<<<4, 256, 0, stream>>>(dsum, z, dfc_b, dvec, dbn4s, dbn4q);
    // decoder
    dec_convt2<32, 64, 50, true, true, true><<<16, 256, 0, stream>>>(
        dvec, dbn4_g, dbn4_b, dbn4s, dbn4q, d4_w, d4_b, h4, dbn3s, dbn3q);
    dec_convt2<64, 128, 54, false, true, true><<<32, 256, 0, stream>>>(
        h4, dbn3_g, dbn3_b, dbn3s, dbn3q, d3_w, d3_b, h5, dbn2s, dbn2q);
    dec_convt2<128, 256, 58, false, true, false><<<64, 256, 0, stream>>>(
        h5, dbn2_g, dbn2_b, dbn2s, dbn2q, d2_w, d2_b, h6, dbn1s, dbn1q);
    k12_dec1<<<16, 256, 0, stream>>>(h6, dbn1_g, dbn1_b, dbn1s, dbn1q, d1_w, d1_b, out);
}